// Round 4
// baseline (1029.611 us; speedup 1.0000x reference)
//
#include <hip/hip_runtime.h>

// Fused LSTM: T=2048, B=1024, I=4, H=10, O=4.
// R4: one chain per wave (1024 waves). h shared register-only:
// DPP quad_perm:[1,0,3,2] (pairwise swap, direction-proof — same pairing as
// R2's verified ds_swizzle xor-1) + cvt_pkrtz + 5x v_readlane -> wave-uniform
// SGPR f16 pairs feeding v_dot2. Zero DS ops in the recurrence.
// x[t] wave-uniform -> scalar loads; FC head + next-x precompute off-path.

typedef __fp16 half2_t __attribute__((ext_vector_type(2)));

#define T_STEPS 2048
#define BATCH   1024
#define HID     10

__device__ __forceinline__ float fdot2(half2_t a, half2_t b, float c) {
    return __builtin_amdgcn_fdot2(a, b, c, false);
}
__device__ __forceinline__ half2_t pkrtz(float a, float b) {
    return __builtin_amdgcn_cvt_pkrtz(a, b);
}
// pre = -log2e * z : sigma(z) = rcp(1 + 2^pre)
__device__ __forceinline__ float sigm_pre(float pre) {
    return __builtin_amdgcn_rcpf(1.0f + __builtin_amdgcn_exp2f(pre));
}
// pre = +2*log2e * z : tanh(z) = 1 - 2*rcp(1 + 2^pre)
__device__ __forceinline__ float tanh_pre(float pre) {
    return 1.0f - 2.0f * __builtin_amdgcn_rcpf(1.0f + __builtin_amdgcn_exp2f(pre));
}

// Broadcast the chain's 10 h values to all lanes as 5 packed-f16 pairs.
// quad_perm:[1,0,3,2] = ctrl 0x0B1: lane i <-> lane i^1 (self-inverse swap,
// identical pairing to R2's ds_swizzle 0x041F). Even lane 2p then holds
// pk = (h_{2p}, h_{2p+1}); readlane at 0/2/4/6/8 broadcasts the 5 pairs.
__device__ __forceinline__ void share_h(float h, half2_t hp[5]) {
    int hi = __builtin_bit_cast(int, h);
    int hn = __builtin_amdgcn_update_dpp(hi, hi, 0x0B1, 0xF, 0xF, true);
    half2_t pk = pkrtz(h, __builtin_bit_cast(float, hn));
    int pki = __builtin_bit_cast(int, pk);
    hp[0] = __builtin_bit_cast(half2_t, __builtin_amdgcn_readlane(pki, 0));
    hp[1] = __builtin_bit_cast(half2_t, __builtin_amdgcn_readlane(pki, 2));
    hp[2] = __builtin_bit_cast(half2_t, __builtin_amdgcn_readlane(pki, 4));
    hp[3] = __builtin_bit_cast(half2_t, __builtin_amdgcn_readlane(pki, 6));
    hp[4] = __builtin_bit_cast(half2_t, __builtin_amdgcn_readlane(pki, 8));
}

__global__ __launch_bounds__(64, 1) void lstm_fused(
    const float* __restrict__ x,    const float* __restrict__ h0,
    const float* __restrict__ c0,   const float* __restrict__ W_ih,
    const float* __restrict__ W_hh, const float* __restrict__ b_ih,
    const float* __restrict__ b_hh, const float* __restrict__ W_fc,
    const float* __restrict__ b_fc, float* __restrict__ out)
{
    const int u_raw = threadIdx.x;               // 0..63
    const int u = (u_raw < HID) ? u_raw : (HID - 1);   // clamp idle lanes' loads
    const int chain = blockIdx.x;                // one chain per wave
    const bool ulive = (u_raw < HID);

    const float LOG2E = 1.4426950408889634f;

    // ---- prologue: load + prescale + f16-pack weights ----
    // PyTorch row order: [0..9]=i, [10..19]=f, [20..29]=g, [30..39]=o
    half2_t wih[4][2], whh[4][5];
    float   bg[4];
    #pragma unroll
    for (int tau = 0; tau < 4; ++tau) {
        const int r = tau * 10 + u;
        const float sc = (tau == 2) ? (2.0f * LOG2E) : (-LOG2E);
        wih[tau][0] = pkrtz(W_ih[r*4+0]*sc, W_ih[r*4+1]*sc);
        wih[tau][1] = pkrtz(W_ih[r*4+2]*sc, W_ih[r*4+3]*sc);
        #pragma unroll
        for (int p = 0; p < 5; ++p)
            whh[tau][p] = pkrtz(W_hh[r*10+2*p]*sc, W_hh[r*10+2*p+1]*sc);
        bg[tau] = (b_ih[r] + b_hh[r]) * sc;
    }
    const int orow = u_raw & 3;
    half2_t wfc[5];
    #pragma unroll
    for (int p = 0; p < 5; ++p)
        wfc[p] = pkrtz(W_fc[orow*10+2*p], W_fc[orow*10+2*p+1]);
    const float bfc = b_fc[orow];

    // ---- initial state ----
    float c = c0[chain*HID + u];
    float h = h0[chain*HID + u];
    half2_t hp[5];
    share_h(h, hp);

    // x[t][chain][0..3]: wave-uniform float4 -> scalar loads
    const float4* x4 = (const float4*)x;
    float4 xc = x4[chain];                 // x[0]
    half2_t vx0 = pkrtz(xc.x, xc.y), vx1 = pkrtz(xc.z, xc.w);
    float pre[4];
    #pragma unroll
    for (int tau = 0; tau < 4; ++tau)
        pre[tau] = fdot2(wih[tau][1], vx1, fdot2(wih[tau][0], vx0, bg[tau]));
    float4 xn = x4[BATCH + chain];         // prefetch x[1]

    float* __restrict__ hs_out = out;                                  // [T*B,4]
    float* __restrict__ hT_out = out + (size_t)T_STEPS * BATCH * 4;    // [B,10]
    float* __restrict__ cT_out = hT_out + BATCH * HID;                 // [B,10]
    const size_t out_base = (size_t)chain * 4 + orow;

    for (int t = 0; t < T_STEPS; ++t) {
        // ---- gates: 4 independent chains of 5 dot2 over SGPR h-pairs ----
        float pi = pre[0], pf = pre[1], pg = pre[2], po = pre[3];
        #pragma unroll
        for (int p = 0; p < 5; ++p) {
            pi = fdot2(whh[0][p], hp[p], pi);
            pf = fdot2(whh[1][p], hp[p], pf);
            pg = fdot2(whh[2][p], hp[p], pg);
            po = fdot2(whh[3][p], hp[p], po);
        }
        const float si = sigm_pre(pi);
        const float sf = sigm_pre(pf);
        const float so = sigm_pre(po);
        const float tg = tanh_pre(pg);
        c = fmaf(sf, c, si * tg);
        h = so * tanh_pre(2.0f * LOG2E * c);

        // ---- share new h (register-only, ~20 cy) ----
        share_h(h, hp);

        // ---- off-path: FC head for step t ----
        float o = bfc;
        #pragma unroll
        for (int p = 0; p < 5; ++p) o = fdot2(wfc[p], hp[p], o);
        if (u_raw < 4)
            hs_out[(size_t)t * (BATCH*4) + out_base] = o;

        // ---- off-path: next-step x precompute ----
        vx0 = pkrtz(xn.x, xn.y); vx1 = pkrtz(xn.z, xn.w);
        #pragma unroll
        for (int tau = 0; tau < 4; ++tau)
            pre[tau] = fdot2(wih[tau][1], vx1, fdot2(wih[tau][0], vx0, bg[tau]));
        const int tn = (t + 2 < T_STEPS) ? (t + 2) : (T_STEPS - 1);
        xn = x4[(size_t)tn * BATCH + chain];
    }

    if (ulive) {
        hT_out[chain*HID + u] = h;
        cT_out[chain*HID + u] = c;
    }
}

extern "C" void kernel_launch(void* const* d_in, const int* in_sizes, int n_in,
                              void* d_out, int out_size, void* d_ws, size_t ws_size,
                              hipStream_t stream) {
    const float* x    = (const float*)d_in[0];
    const float* h0   = (const float*)d_in[1];
    const float* c0   = (const float*)d_in[2];
    const float* W_ih = (const float*)d_in[3];
    const float* W_hh = (const float*)d_in[4];
    const float* b_ih = (const float*)d_in[5];
    const float* b_hh = (const float*)d_in[6];
    const float* W_fc = (const float*)d_in[7];
    const float* b_fc = (const float*)d_in[8];
    float* out = (float*)d_out;

    lstm_fused<<<dim3(BATCH), dim3(64), 0, stream>>>(
        x, h0, c0, W_ih, W_hh, b_ih, b_hh, W_fc, b_fc, out);
}

// Round 5
// 519.772 us; speedup vs baseline: 1.9809x; 1.9809x over previous
//
#include <hip/hip_runtime.h>

// Fused LSTM: T=2048, B=1024, I=4, H=10, O=4.
// R5: R4 (DPP quad_perm + readlane h-share, zero DS ops) + 8-deep VECTOR-load
// ring prefetch for x. R2/R4 were pinned at ~1 load-miss latency per step
// (890/1207 cy) because prefetch depth was 1 (and R4's s_load waits are
// all-or-nothing on lgkmcnt). Lane-dependent addresses force global_load
// (ordered vmcnt -> fine-grained waits); depth 8 gives ~8 steps of slack.

typedef __fp16 half2_t __attribute__((ext_vector_type(2)));

#define T_STEPS 2048
#define BATCH   1024
#define HID     10
#define DPRE    8    // x prefetch ring depth (T_STEPS % DPRE == 0)

__device__ __forceinline__ float fdot2(half2_t a, half2_t b, float c) {
    return __builtin_amdgcn_fdot2(a, b, c, false);
}
__device__ __forceinline__ half2_t pkrtz(float a, float b) {
    return __builtin_amdgcn_cvt_pkrtz(a, b);
}
__device__ __forceinline__ float rl_f(float v, int l) {
    return __builtin_bit_cast(float, __builtin_amdgcn_readlane(__builtin_bit_cast(int, v), l));
}
// pre = -log2e * z : sigma(z) = rcp(1 + 2^pre)
__device__ __forceinline__ float sigm_pre(float pre) {
    return __builtin_amdgcn_rcpf(1.0f + __builtin_amdgcn_exp2f(pre));
}
// pre = +2*log2e * z : tanh(z) = 1 - 2*rcp(1 + 2^pre)
__device__ __forceinline__ float tanh_pre(float pre) {
    return 1.0f - 2.0f * __builtin_amdgcn_rcpf(1.0f + __builtin_amdgcn_exp2f(pre));
}

// Broadcast the chain's 10 h values to all lanes as 5 packed-f16 pairs.
// quad_perm:[1,0,3,2] (ctrl 0x0B1): lane i <-> i^1 (verified R4). Even lane
// 2p holds (h_2p, h_2p+1); readlane @ 0/2/4/6/8 -> wave-uniform SGPR pairs.
__device__ __forceinline__ void share_h(float h, half2_t hp[5]) {
    int hi = __builtin_bit_cast(int, h);
    int hn = __builtin_amdgcn_update_dpp(hi, hi, 0x0B1, 0xF, 0xF, true);
    half2_t pk = pkrtz(h, __builtin_bit_cast(float, hn));
    int pki = __builtin_bit_cast(int, pk);
    hp[0] = __builtin_bit_cast(half2_t, __builtin_amdgcn_readlane(pki, 0));
    hp[1] = __builtin_bit_cast(half2_t, __builtin_amdgcn_readlane(pki, 2));
    hp[2] = __builtin_bit_cast(half2_t, __builtin_amdgcn_readlane(pki, 4));
    hp[3] = __builtin_bit_cast(half2_t, __builtin_amdgcn_readlane(pki, 6));
    hp[4] = __builtin_bit_cast(half2_t, __builtin_amdgcn_readlane(pki, 8));
}

__global__ __launch_bounds__(64, 1) void lstm_fused(
    const float* __restrict__ x,    const float* __restrict__ h0,
    const float* __restrict__ c0,   const float* __restrict__ W_ih,
    const float* __restrict__ W_hh, const float* __restrict__ b_ih,
    const float* __restrict__ b_hh, const float* __restrict__ W_fc,
    const float* __restrict__ b_fc, float* __restrict__ out)
{
    const int u_raw = threadIdx.x;               // 0..63
    const int u = (u_raw < HID) ? u_raw : (HID - 1);   // clamp idle lanes' loads
    const int chain = blockIdx.x;                // one chain per wave
    const bool ulive = (u_raw < HID);

    const float LOG2E = 1.4426950408889634f;

    // ---- prologue: load + prescale + f16-pack weights ----
    // PyTorch row order: [0..9]=i, [10..19]=f, [20..29]=g, [30..39]=o
    half2_t wih[4][2], whh[4][5];
    float   bg[4];
    #pragma unroll
    for (int tau = 0; tau < 4; ++tau) {
        const int r = tau * 10 + u;
        const float sc = (tau == 2) ? (2.0f * LOG2E) : (-LOG2E);
        wih[tau][0] = pkrtz(W_ih[r*4+0]*sc, W_ih[r*4+1]*sc);
        wih[tau][1] = pkrtz(W_ih[r*4+2]*sc, W_ih[r*4+3]*sc);
        #pragma unroll
        for (int p = 0; p < 5; ++p)
            whh[tau][p] = pkrtz(W_hh[r*10+2*p]*sc, W_hh[r*10+2*p+1]*sc);
        bg[tau] = (b_ih[r] + b_hh[r]) * sc;
    }
    const int orow = u_raw & 3;
    half2_t wfc[5];
    #pragma unroll
    for (int p = 0; p < 5; ++p)
        wfc[p] = pkrtz(W_fc[orow*10+2*p], W_fc[orow*10+2*p+1]);
    const float bfc = b_fc[orow];

    // ---- initial state ----
    float c = c0[chain*HID + u];
    float h = h0[chain*HID + u];
    half2_t hp[5];
    share_h(h, hp);

    // pre[] for step 0 from x[0] (one-time uniform load)
    const float4* x4 = (const float4*)x;
    float4 x0 = x4[chain];
    half2_t vx0 = pkrtz(x0.x, x0.y), vx1 = pkrtz(x0.z, x0.w);
    float pre[4];
    #pragma unroll
    for (int tau = 0; tau < 4; ++tau)
        pre[tau] = fdot2(wih[tau][1], vx1, fdot2(wih[tau][0], vx0, bg[tau]));

    // ---- x prefetch ring: lane l loads component (l&3) of x[t][chain] ----
    // Lane-dependent address -> global_load_dword (ordered vmcnt), 16 B/wave.
    const int xl = u_raw & 3;
    const float* __restrict__ xs = x + (size_t)chain * 4 + xl;  // + t*BATCH*4
    float xv[DPRE];
    #pragma unroll
    for (int j = 0; j < DPRE; ++j)
        xv[j] = xs[(size_t)(1 + j) * (BATCH * 4)];   // x[1..DPRE]

    float* __restrict__ hs_out = out;                                  // [T*B,4]
    float* __restrict__ hT_out = out + (size_t)T_STEPS * BATCH * 4;    // [B,10]
    float* __restrict__ cT_out = hT_out + BATCH * HID;                 // [B,10]
    const size_t out_base = (size_t)chain * 4 + orow;

    for (int tb = 0; tb < T_STEPS; tb += DPRE) {
        #pragma unroll
        for (int j = 0; j < DPRE; ++j) {
            const int t = tb + j;
            // ---- critical cycle: gates -> activations -> c -> h ----
            float pi = pre[0], pf = pre[1], pg = pre[2], po = pre[3];
            #pragma unroll
            for (int p = 0; p < 5; ++p) {
                pi = fdot2(whh[0][p], hp[p], pi);
                pf = fdot2(whh[1][p], hp[p], pf);
                pg = fdot2(whh[2][p], hp[p], pg);
                po = fdot2(whh[3][p], hp[p], po);
            }
            const float si = sigm_pre(pi);
            const float sf = sigm_pre(pf);
            const float so = sigm_pre(po);
            const float tg = tanh_pre(pg);
            c = fmaf(sf, c, si * tg);
            h = so * tanh_pre(2.0f * LOG2E * c);
            share_h(h, hp);

            // ---- off-path: FC head for step t ----
            float o = bfc;
            #pragma unroll
            for (int p = 0; p < 5; ++p) o = fdot2(wfc[p], hp[p], o);
            if (u_raw < 4)
                hs_out[(size_t)t * (BATCH*4) + out_base] = o;

            // ---- off-path: consume ring slot j = x[t+1] -> pre for t+1 ----
            const float xs0 = rl_f(xv[j], 0);
            const float xs1 = rl_f(xv[j], 1);
            const float xs2 = rl_f(xv[j], 2);
            const float xs3 = rl_f(xv[j], 3);
            vx0 = pkrtz(xs0, xs1); vx1 = pkrtz(xs2, xs3);
            #pragma unroll
            for (int tau = 0; tau < 4; ++tau)
                pre[tau] = fdot2(wih[tau][1], vx1, fdot2(wih[tau][0], vx0, bg[tau]));

            // ---- reissue: load x[t+1+DPRE] into slot j ----
            int tl = t + 1 + DPRE;
            if (tl > T_STEPS - 1) tl = T_STEPS - 1;    // tail clamp (unused values)
            xv[j] = xs[(size_t)tl * (BATCH * 4)];
        }
    }

    if (ulive) {
        hT_out[chain*HID + u] = h;
        cT_out[chain*HID + u] = c;
    }
}

extern "C" void kernel_launch(void* const* d_in, const int* in_sizes, int n_in,
                              void* d_out, int out_size, void* d_ws, size_t ws_size,
                              hipStream_t stream) {
    const float* x    = (const float*)d_in[0];
    const float* h0   = (const float*)d_in[1];
    const float* c0   = (const float*)d_in[2];
    const float* W_ih = (const float*)d_in[3];
    const float* W_hh = (const float*)d_in[4];
    const float* b_ih = (const float*)d_in[5];
    const float* b_hh = (const float*)d_in[6];
    const float* W_fc = (const float*)d_in[7];
    const float* b_fc = (const float*)d_in[8];
    float* out = (float*)d_out;

    lstm_fused<<<dim3(BATCH), dim3(64), 0, stream>>>(
        x, h0, c0, W_ih, W_hh, b_ih, b_hh, W_fc, b_fc, out);
}

// Round 6
// 421.960 us; speedup vs baseline: 2.4401x; 1.2318x over previous
//
#include <hip/hip_runtime.h>

// Fused LSTM: T=2048, B=1024, I=4, H=10, O=4.
// R6: gate-parallel lane layout. Lane 4u+g owns gate-row g*10+u (40 active
// lanes): gates = 5 dot2/step (was 20), one activation block/lane (trans
// blocks 10 -> 4 per step). Gate products combined via quad_perm DPP
// broadcasts (unit u's i,f,g,o live in aligned quad 4u..4u+3). h shared via
// DPP row_shl:4 + pkrtz + 5 readlane (R4-verified pattern, direction per R3
// empirics: row_shr:1 = in[i-1] => row_shl:4 = in[i+4]). 8-deep vector-load
// ring for x (R5-verified). One chain per wave, 1024 waves.

typedef __fp16 half2_t __attribute__((ext_vector_type(2)));

#define T_STEPS 2048
#define BATCH   1024
#define HID     10
#define DPRE    8    // x prefetch ring depth (T_STEPS % DPRE == 0)

__device__ __forceinline__ float fdot2(half2_t a, half2_t b, float c) {
    return __builtin_amdgcn_fdot2(a, b, c, false);
}
__device__ __forceinline__ half2_t pkrtz(float a, float b) {
    return __builtin_amdgcn_cvt_pkrtz(a, b);
}
__device__ __forceinline__ float rl_f(float v, int l) {
    return __builtin_bit_cast(float, __builtin_amdgcn_readlane(__builtin_bit_cast(int, v), l));
}
template <int CTRL>
__device__ __forceinline__ float dpp_f(float v) {
    int vi = __builtin_bit_cast(int, v);
    return __builtin_bit_cast(float, __builtin_amdgcn_update_dpp(vi, vi, CTRL, 0xF, 0xF, true));
}

__global__ __launch_bounds__(64, 1) void lstm_fused(
    const float* __restrict__ x,    const float* __restrict__ h0,
    const float* __restrict__ c0,   const float* __restrict__ W_ih,
    const float* __restrict__ W_hh, const float* __restrict__ b_ih,
    const float* __restrict__ b_hh, const float* __restrict__ W_fc,
    const float* __restrict__ b_fc, float* __restrict__ out)
{
    const int lane  = threadIdx.x;               // 0..63
    const int g     = lane & 3;                  // gate index i,f,g,o
    const int u     = (lane < 40) ? (lane >> 2) : 9;   // hidden unit (clamped)
    const int chain = blockIdx.x;                // one chain per wave

    const float LOG2E = 1.4426950408889634f;

    // ---- prologue: this lane's gate-row r = g*10+u, prescaled + f16-packed ----
    // PyTorch row order: [0..9]=i, [10..19]=f, [20..29]=g, [30..39]=o
    const int   r  = g * 10 + u;
    const float sc = (g == 2) ? (2.0f * LOG2E) : (-LOG2E);
    half2_t wih[2], whh[5];
    wih[0] = pkrtz(W_ih[r*4+0]*sc, W_ih[r*4+1]*sc);
    wih[1] = pkrtz(W_ih[r*4+2]*sc, W_ih[r*4+3]*sc);
    #pragma unroll
    for (int p = 0; p < 5; ++p)
        whh[p] = pkrtz(W_hh[r*10+2*p]*sc, W_hh[r*10+2*p+1]*sc);
    const float bg = (b_ih[r] + b_hh[r]) * sc;
    // activation: act = fma(am, rcp(1+exp2(pre)), aa): sigm=(1,0), tanh=(-2,1)
    const float am = (g == 2) ? -2.0f : 1.0f;
    const float aa = (g == 2) ?  1.0f : 0.0f;

    const int orow = lane & 3;
    half2_t wfc[5];
    #pragma unroll
    for (int p = 0; p < 5; ++p)
        wfc[p] = pkrtz(W_fc[orow*10+2*p], W_fc[orow*10+2*p+1]);
    const float bfc = b_fc[orow];

    // ---- initial state (same value in all 4 lanes of unit u's quad) ----
    float c = c0[chain*HID + u];
    float h = h0[chain*HID + u];
    // share h: lane 8p packs (h_{2p}, h_{2p+1}) via row_shl:4; readlane @ 0/8/16/24/32
    half2_t hp[5];
    {
        float hn = dpp_f<0x104>(h);              // row_shl:4 -> in[i+4]
        half2_t pk = pkrtz(h, hn);
        int pki = __builtin_bit_cast(int, pk);
        hp[0] = __builtin_bit_cast(half2_t, __builtin_amdgcn_readlane(pki, 0));
        hp[1] = __builtin_bit_cast(half2_t, __builtin_amdgcn_readlane(pki, 8));
        hp[2] = __builtin_bit_cast(half2_t, __builtin_amdgcn_readlane(pki, 16));
        hp[3] = __builtin_bit_cast(half2_t, __builtin_amdgcn_readlane(pki, 24));
        hp[4] = __builtin_bit_cast(half2_t, __builtin_amdgcn_readlane(pki, 32));
    }

    // prex for step 0 from x[0] (one-time uniform load)
    const float4* x4 = (const float4*)x;
    float4 x0 = x4[chain];
    half2_t vx0 = pkrtz(x0.x, x0.y), vx1 = pkrtz(x0.z, x0.w);
    float prex = fdot2(wih[1], vx1, fdot2(wih[0], vx0, bg));

    // ---- x prefetch ring: lane l loads component (l&3) of x[t][chain] ----
    const int xl = lane & 3;
    const float* __restrict__ xs = x + (size_t)chain * 4 + xl;  // + t*BATCH*4
    float xv[DPRE];
    #pragma unroll
    for (int j = 0; j < DPRE; ++j)
        xv[j] = xs[(size_t)(1 + j) * (BATCH * 4)];   // x[1..DPRE]

    float* __restrict__ hs_out = out;                                  // [T*B,4]
    float* __restrict__ hT_out = out + (size_t)T_STEPS * BATCH * 4;    // [B,10]
    float* __restrict__ cT_out = hT_out + BATCH * HID;                 // [B,10]
    const size_t out_base = (size_t)chain * 4 + orow;

    for (int tb = 0; tb < T_STEPS; tb += DPRE) {
        #pragma unroll
        for (int j = 0; j < DPRE; ++j) {
            const int t = tb + j;
            // ---- critical cycle: 5 dot2 -> 1 act -> quad bcast -> c -> h ----
            float pre = prex;
            #pragma unroll
            for (int p = 0; p < 5; ++p) pre = fdot2(whh[p], hp[p], pre);
            const float rr  = __builtin_amdgcn_rcpf(1.0f + __builtin_amdgcn_exp2f(pre));
            const float act = fmaf(am, rr, aa);
            const float si = dpp_f<0x000>(act);   // quad_perm [0,0,0,0]
            const float sf = dpp_f<0x055>(act);   // quad_perm [1,1,1,1]
            const float tg = dpp_f<0x0AA>(act);   // quad_perm [2,2,2,2]
            const float so = dpp_f<0x0FF>(act);   // quad_perm [3,3,3,3]
            c = fmaf(sf, c, si * tg);
            const float r2 = __builtin_amdgcn_rcpf(
                1.0f + __builtin_amdgcn_exp2f(c * (2.0f * LOG2E)));
            h = so * fmaf(-2.0f, r2, 1.0f);
            // share new h
            float hn = dpp_f<0x104>(h);
            half2_t pk = pkrtz(h, hn);
            int pki = __builtin_bit_cast(int, pk);
            hp[0] = __builtin_bit_cast(half2_t, __builtin_amdgcn_readlane(pki, 0));
            hp[1] = __builtin_bit_cast(half2_t, __builtin_amdgcn_readlane(pki, 8));
            hp[2] = __builtin_bit_cast(half2_t, __builtin_amdgcn_readlane(pki, 16));
            hp[3] = __builtin_bit_cast(half2_t, __builtin_amdgcn_readlane(pki, 24));
            hp[4] = __builtin_bit_cast(half2_t, __builtin_amdgcn_readlane(pki, 32));

            // ---- off-path: FC head for step t (any 4 lanes; use 0..3) ----
            float o = bfc;
            #pragma unroll
            for (int p = 0; p < 5; ++p) o = fdot2(wfc[p], hp[p], o);
            if (lane < 4)
                hs_out[(size_t)t * (BATCH*4) + out_base] = o;

            // ---- off-path: consume ring slot j = x[t+1] -> prex for t+1 ----
            const float xs0 = rl_f(xv[j], 0);
            const float xs1 = rl_f(xv[j], 1);
            const float xs2 = rl_f(xv[j], 2);
            const float xs3 = rl_f(xv[j], 3);
            vx0 = pkrtz(xs0, xs1); vx1 = pkrtz(xs2, xs3);
            prex = fdot2(wih[1], vx1, fdot2(wih[0], vx0, bg));

            // ---- reissue: load x[t+1+DPRE] into slot j ----
            int tl = t + 1 + DPRE;
            if (tl > T_STEPS - 1) tl = T_STEPS - 1;    // tail clamp (values unused)
            xv[j] = xs[(size_t)tl * (BATCH * 4)];
        }
    }

    // final state: lane 4u (g==0) of each live unit stores h,c
    if (lane < 40 && (lane & 3) == 0) {
        hT_out[chain*HID + u] = h;
        cT_out[chain*HID + u] = c;
    }
}

extern "C" void kernel_launch(void* const* d_in, const int* in_sizes, int n_in,
                              void* d_out, int out_size, void* d_ws, size_t ws_size,
                              hipStream_t stream) {
    const float* x    = (const float*)d_in[0];
    const float* h0   = (const float*)d_in[1];
    const float* c0   = (const float*)d_in[2];
    const float* W_ih = (const float*)d_in[3];
    const float* W_hh = (const float*)d_in[4];
    const float* b_ih = (const float*)d_in[5];
    const float* b_hh = (const float*)d_in[6];
    const float* W_fc = (const float*)d_in[7];
    const float* b_fc = (const float*)d_in[8];
    float* out = (float*)d_out;

    lstm_fused<<<dim3(BATCH), dim3(64), 0, stream>>>(
        x, h0, c0, W_ih, W_hh, b_ih, b_hh, W_fc, b_fc, out);
}

// Round 7
// 376.210 us; speedup vs baseline: 2.7368x; 1.1216x over previous
//
#include <hip/hip_runtime.h>

// Fused LSTM: T=2048, B=1024, I=4, H=10, O=4.
// R7 = R6 (gate-parallel lanes, quad_perm combine, row_shl:4+readlane h-share,
// 8-deep vector ring) + critical-cycle latency cuts:
//  - gate dot chain split 3+2 (+add)          [-2 dot latencies]
//  - cell state kept pre-scaled C=2log2e*c    [-1 serial mul; folded into act_g]
//  - h = fma(-2*so, r2, so), so2 off-path     [-1 serial mul]
//  - x-consume via quad-DPP f32 fma (no readlane/pkrtz) scheduled in the
//    readlane hazard shadow; FC head moved after it
//  - main loop unclamped, tail loop (last 16 steps) clamped

typedef __fp16 half2_t __attribute__((ext_vector_type(2)));

#define T_STEPS 2048
#define BATCH   1024
#define HID     10
#define DPRE    8    // x prefetch ring depth

__device__ __forceinline__ float fdot2(half2_t a, half2_t b, float c) {
    return __builtin_amdgcn_fdot2(a, b, c, false);
}
__device__ __forceinline__ half2_t pkrtz(float a, float b) {
    return __builtin_amdgcn_cvt_pkrtz(a, b);
}
template <int CTRL>
__device__ __forceinline__ float dpp_f(float v) {
    int vi = __builtin_bit_cast(int, v);
    return __builtin_bit_cast(float, __builtin_amdgcn_update_dpp(vi, vi, CTRL, 0xF, 0xF, true));
}
__device__ __forceinline__ half2_t rl_h2(int pki, int l) {
    return __builtin_bit_cast(half2_t, __builtin_amdgcn_readlane(pki, l));
}

__global__ __launch_bounds__(64, 1) void lstm_fused(
    const float* __restrict__ x,    const float* __restrict__ h0,
    const float* __restrict__ c0,   const float* __restrict__ W_ih,
    const float* __restrict__ W_hh, const float* __restrict__ b_ih,
    const float* __restrict__ b_hh, const float* __restrict__ W_fc,
    const float* __restrict__ b_fc, float* __restrict__ out)
{
    const int lane  = threadIdx.x;               // 0..63
    const int g     = lane & 3;                  // gate index i,f,g,o
    const int u     = (lane < 40) ? (lane >> 2) : 9;   // hidden unit (clamped)
    const int chain = blockIdx.x;                // one chain per wave

    const float LOG2E  = 1.4426950408889634f;    // log2(e)
    const float TWOL2E = 2.8853900817779268f;    // 2*log2(e)

    // ---- prologue: this lane's gate-row r = g*10+u, prescaled ----
    // PyTorch row order: [0..9]=i, [10..19]=f, [20..29]=g, [30..39]=o
    const int   r  = g * 10 + u;
    const float sc = (g == 2) ? TWOL2E : (-LOG2E);
    float wx0 = W_ih[r*4+0]*sc, wx1 = W_ih[r*4+1]*sc;
    float wx2 = W_ih[r*4+2]*sc, wx3 = W_ih[r*4+3]*sc;
    half2_t whh[5];
    #pragma unroll
    for (int p = 0; p < 5; ++p)
        whh[p] = pkrtz(W_hh[r*10+2*p]*sc, W_hh[r*10+2*p+1]*sc);
    const float bg = (b_ih[r] + b_hh[r]) * sc;
    // activation constants: act = fma(am, rr, aa) where rr = rcp(1+exp2(pre))
    //   sigmoid lanes: act = rr                      -> am=1,  aa=0
    //   g lane: act = 2log2e*tanh = 2log2e*(1-2rr)   -> am=-4log2e, aa=2log2e
    const float am = (g == 2) ? (-2.0f * TWOL2E) : 1.0f;
    const float aa = (g == 2) ? TWOL2E : 0.0f;

    const int orow = lane & 3;
    half2_t wfc[5];
    #pragma unroll
    for (int p = 0; p < 5; ++p)
        wfc[p] = pkrtz(W_fc[orow*10+2*p], W_fc[orow*10+2*p+1]);
    const float bfc = b_fc[orow];

    // ---- initial state (replicated across unit u's quad) ----
    float C = TWOL2E * c0[chain*HID + u];        // pre-scaled cell state
    float h = h0[chain*HID + u];
    half2_t hp[5];
    {
        float hn = dpp_f<0x104>(h);              // row_shl:4 -> in[i+4] (R6-verified)
        int pki = __builtin_bit_cast(int, pkrtz(h, hn));
        hp[0] = rl_h2(pki, 0);  hp[1] = rl_h2(pki, 8);  hp[2] = rl_h2(pki, 16);
        hp[3] = rl_h2(pki, 24); hp[4] = rl_h2(pki, 32);
    }

    // prex for step 0 from x[0] (one-time uniform load)
    const float4* x4 = (const float4*)x;
    float4 x0 = x4[chain];
    float prex = fmaf(wx3, x0.w, fmaf(wx2, x0.z, fmaf(wx1, x0.y, fmaf(wx0, x0.x, bg))));

    // ---- x prefetch ring: lane l loads component (l&3) of x[t][chain] ----
    const int xl = lane & 3;
    const float* __restrict__ xs = x + (size_t)chain * 4 + xl;  // + t*BATCH*4
    float xv[DPRE];
    #pragma unroll
    for (int j = 0; j < DPRE; ++j)
        xv[j] = xs[(size_t)(1 + j) * (BATCH * 4)];   // x[1..DPRE]

    float* __restrict__ hs_out = out;                                  // [T*B,4]
    float* __restrict__ hT_out = out + (size_t)T_STEPS * BATCH * 4;    // [B,10]
    float* __restrict__ cT_out = hT_out + BATCH * HID;                 // [B,10]
    const size_t out_base = (size_t)chain * 4 + orow;

#define STEP(T_, J_, CLAMP_) do {                                               \
    /* critical cycle: split dot chains -> act -> quad bcast -> C -> h */       \
    float pa = fdot2(whh[1], hp[1], fdot2(whh[0], hp[0], prex));                \
    float pb = fdot2(whh[4], hp[4], fdot2(whh[3], hp[3],                        \
               fdot2(whh[2], hp[2], 0.0f)));                                    \
    const float pre = pa + pb;                                                  \
    const float rr  = __builtin_amdgcn_rcpf(1.0f + __builtin_amdgcn_exp2f(pre));\
    const float act = fmaf(am, rr, aa);                                         \
    const float si  = dpp_f<0x000>(act);                                        \
    const float sf  = dpp_f<0x055>(act);                                        \
    const float tg2 = dpp_f<0x0AA>(act);   /* = 2log2e*tanh(g) */               \
    const float so  = dpp_f<0x0FF>(act);                                        \
    C = fmaf(sf, C, si * tg2);                                                  \
    const float r2  = __builtin_amdgcn_rcpf(1.0f + __builtin_amdgcn_exp2f(C));  \
    const float so2 = -2.0f * so;          /* off-path */                       \
    h = fmaf(so2, r2, so);                                                      \
    /* share new h */                                                           \
    float hn = dpp_f<0x104>(h);                                                 \
    int pki = __builtin_bit_cast(int, pkrtz(h, hn));                            \
    hp[0] = rl_h2(pki, 0);  hp[1] = rl_h2(pki, 8);  hp[2] = rl_h2(pki, 16);     \
    hp[3] = rl_h2(pki, 24); hp[4] = rl_h2(pki, 32);                             \
    /* hp-independent work in the readlane hazard shadow: x-consume + reissue */\
    float xb = xv[J_];                                                          \
    prex = fmaf(dpp_f<0x000>(xb), wx0, bg);                                     \
    prex = fmaf(dpp_f<0x055>(xb), wx1, prex);                                   \
    prex = fmaf(dpp_f<0x0AA>(xb), wx2, prex);                                   \
    prex = fmaf(dpp_f<0x0FF>(xb), wx3, prex);                                   \
    {                                                                           \
        int tl = (T_) + 1 + DPRE;                                               \
        if (CLAMP_) tl = (tl > T_STEPS - 1) ? (T_STEPS - 1) : tl;               \
        xv[J_] = xs[(size_t)tl * (BATCH * 4)];                                  \
    }                                                                           \
    /* FC head (consumes new hp) */                                             \
    float o = fdot2(wfc[4], hp[4], fdot2(wfc[3], hp[3], fdot2(wfc[2], hp[2],    \
              fdot2(wfc[1], hp[1], fdot2(wfc[0], hp[0], bfc)))));               \
    if (lane < 4)                                                               \
        hs_out[(size_t)(T_) * (BATCH*4) + out_base] = o;                        \
} while (0)

    // main loop: loads never need clamping (t <= 2031 -> tl <= 2040)
    for (int tb = 0; tb < T_STEPS - 2*DPRE; tb += DPRE) {
        #pragma unroll
        for (int j = 0; j < DPRE; ++j) STEP(tb + j, j, false);
    }
    // tail: last 16 steps, clamped reissue (loaded values never consumed)
    for (int t = T_STEPS - 2*DPRE; t < T_STEPS; ++t)
        STEP(t, t & (DPRE - 1), true);
#undef STEP

    // final state: lane 4u (g==0) of each live unit stores h,c
    if (lane < 40 && (lane & 3) == 0) {
        hT_out[chain*HID + u] = h;
        cT_out[chain*HID + u] = C * 0.34657359027997264f;  // c = C * ln2/2
    }
}

extern "C" void kernel_launch(void* const* d_in, const int* in_sizes, int n_in,
                              void* d_out, int out_size, void* d_ws, size_t ws_size,
                              hipStream_t stream) {
    const float* x    = (const float*)d_in[0];
    const float* h0   = (const float*)d_in[1];
    const float* c0   = (const float*)d_in[2];
    const float* W_ih = (const float*)d_in[3];
    const float* W_hh = (const float*)d_in[4];
    const float* b_ih = (const float*)d_in[5];
    const float* b_hh = (const float*)d_in[6];
    const float* W_fc = (const float*)d_in[7];
    const float* b_fc = (const float*)d_in[8];
    float* out = (float*)d_out;

    lstm_fused<<<dim3(BATCH), dim3(64), 0, stream>>>(
        x, h0, c0, W_ih, W_hh, b_ih, b_hh, W_fc, b_fc, out);
}